// Round 1
// baseline (283.941 us; speedup 1.0000x reference)
//
#include <hip/hip_runtime.h>
#include <math.h>

#define DIM   32
#define KC    32
#define NPTS  131072
#define NPB   512      // point blocks, 256 pts each
#define NPAIR 1024
#define DLOG2PI 58.81206612467475   // 32 * ln(2*pi)

// merge (m,s) representing s*exp(m) with (m2,s2)
static __device__ __forceinline__ void lse_merge(double& m, double& s, double m2, double s2) {
  if (m2 > m) { s = s * exp(m - m2) + s2; m = m2; }
  else        { s = s + s2 * exp(m2 - m); }
}

// ---------------- setup: per-cluster Sigma, chol, Linv (packed), c, logdet ----------
__global__ __launch_bounds__(64) void setup_kernel(
    const float* __restrict__ means, const float* __restrict__ chols,
    float* __restrict__ Bpk, float* __restrict__ cvec, float* __restrict__ logdetv,
    double* __restrict__ Sigma)
{
  int k = blockIdx.x, tid = threadIdx.x;
  __shared__ float  Cs[1024];
  __shared__ double S[1024];     // Sigma -> becomes L (lower)
  __shared__ double Binv[1024];
  for (int i = tid; i < 1024; i += 64) Cs[i] = chols[k*1024 + i];
  __syncthreads();
  for (int i = tid; i < 1024; i += 64) {
    int d = i >> 5, e = i & 31;
    double acc = (d == e) ? 1.0 : 0.0;
    for (int m = 0; m < 32; m++) acc += (double)Cs[d*32+m] * (double)Cs[e*32+m];
    S[i] = acc;
    Sigma[k*1024 + i] = acc;
  }
  __syncthreads();
  // right-looking cholesky (lower)
  for (int j = 0; j < 32; j++) {
    if (tid == 0) S[j*32+j] = sqrt(S[j*32+j]);
    __syncthreads();
    if (tid > j && tid < 32) S[tid*32+j] /= S[j*32+j];
    __syncthreads();
    if (tid > j && tid < 32) {
      double l = S[tid*32+j];
      for (int e = j+1; e <= tid; e++) S[tid*32+e] -= l * S[e*32+j];
    }
    __syncthreads();
  }
  if (tid == 0) {
    double ld = 0.0;
    for (int j = 0; j < 32; j++) ld += log(S[j*32+j]);
    logdetv[k] = (float)(2.0 * ld);
  }
  // invert L: thread c solves column c of L*B = I
  if (tid < 32) {
    int c = tid;
    for (int d = 0; d < 32; d++) {
      if (d < c) { Binv[d*32+c] = 0.0; continue; }
      double acc = (d == c) ? 1.0 : 0.0;
      for (int j2 = c; j2 < d; j2++) acc -= S[d*32+j2] * Binv[j2*32+c];
      Binv[d*32+c] = acc / S[d*32+d];
    }
  }
  __syncthreads();
  // pack lower-triangular B (row-major packed: idx = d(d+1)/2 + j)
  for (int i = tid; i < 528; i += 64) {
    int d = 0;
    while (i >= (d+1)*(d+2)/2) d++;
    int j = i - d*(d+1)/2;
    Bpk[k*528 + i] = (float)Binv[d*32 + j];
  }
  if (tid < 32) {
    double acc = 0.0;
    for (int j = 0; j <= tid; j++) acc += Binv[tid*32+j] * (double)means[k*32+j];
    cvec[k*32 + tid] = (float)acc;
  }
}

// ---------------- work: point blocks (<NPB) + pair blocks (>=NPB) -------------------
__global__ __launch_bounds__(256) void work_kernel(
    const float* __restrict__ X, const float* __restrict__ means, const float* __restrict__ wts,
    const float* __restrict__ Bpk, const float* __restrict__ cvec, const float* __restrict__ logdetv,
    const double* __restrict__ Sigma, double* __restrict__ pairv, double* __restrict__ partials)
{
  __shared__ __align__(16) char smem[36032];
  __shared__ double redm[4], reds[4];
  int tid = threadIdx.x;
  if (blockIdx.x < NPB) {
    // ---- points role: 256 points, all 32 clusters ----
    float* xs = (float*)smem;                   // 256 x 33 (padded)
    float* bs = (float*)(smem + 33792);         // 528
    float* cs = (float*)(smem + 33792 + 2112);  // 32
    const float* Xg = X + (size_t)blockIdx.x * (256*32);
    for (int i = tid; i < 256*32; i += 256) xs[(i >> 5)*33 + (i & 31)] = Xg[i];
    __syncthreads();
    float x[32];
    #pragma unroll
    for (int j = 0; j < 32; j++) x[j] = xs[tid*33 + j];
    float mF = -1e30f, sF = 0.0f;
    for (int k = 0; k < KC; k++) {
      __syncthreads();   // previous iteration's bs reads done
      for (int i = tid; i < 528; i += 256) bs[i] = Bpk[k*528 + i];
      if (tid < 32) cs[tid] = cvec[k*32 + tid];
      __syncthreads();
      float maha = 0.0f; int off = 0;
      #pragma unroll
      for (int d = 0; d < 32; d++) {
        float y = -cs[d];
        #pragma unroll
        for (int jj = 0; jj <= d; jj++) y = fmaf(bs[off + jj], x[jj], y);
        off += d + 1;
        maha = fmaf(y, y, maha);
      }
      float g  = -0.5f * (maha + logdetv[k] + 58.8120661f);
      float wk = wts[k];
      float M  = fmaxf(mF, g);
      sF = sF * __expf(mF - M) + wk * __expf(g - M);
      mF = M;
    }
    // v = log(s_i^2) = 2*mF + 2*log|sF|
    double vm, vs = 1.0;
    if (sF != 0.0f) vm = 2.0 * (double)mF + 2.0 * log(fabs((double)sF));
    else            vm = -1e30;
    #pragma unroll
    for (int off2 = 32; off2 > 0; off2 >>= 1) {
      double m2 = __shfl_down(vm, off2);
      double s2 = __shfl_down(vs, off2);
      lse_merge(vm, vs, m2, s2);
    }
    if ((tid & 63) == 0) { redm[tid >> 6] = vm; reds[tid >> 6] = vs; }
    __syncthreads();
    if (tid == 0) {
      for (int w = 1; w < 4; w++) lse_merge(vm, vs, redm[w], reds[w]);
      partials[2*blockIdx.x]   = vm;
      partials[2*blockIdx.x+1] = vs;
    }
  } else {
    // ---- pairs role: chol(Sigma_i + Sigma_j), maha(dmu), logdet ----
    int pid = blockIdx.x - NPB;
    int pi = pid >> 5, pj = pid & 31;
    double* S = (double*)smem;   // 32x32
    for (int t = tid; t < 1024; t += 256) S[t] = Sigma[pi*1024 + t] + Sigma[pj*1024 + t];
    __syncthreads();
    for (int jc = 0; jc < 32; jc++) {
      if (tid == 0) S[jc*32+jc] = sqrt(S[jc*32+jc]);
      __syncthreads();
      if (tid > jc && tid < 32) S[tid*32+jc] /= S[jc*32+jc];
      __syncthreads();
      if (tid > jc && tid < 32) {
        double l = S[tid*32+jc];
        for (int e = jc+1; e <= tid; e++) S[tid*32+e] -= l * S[e*32+jc];
      }
      __syncthreads();
    }
    if (tid == 0) {
      double y[32];
      double ld = 0.0, maha = 0.0;
      #pragma unroll
      for (int d = 0; d < 32; d++) {
        double acc = (double)means[pi*32+d] - (double)means[pj*32+d];
        #pragma unroll
        for (int j2 = 0; j2 < d; j2++) acc -= S[d*32+j2] * y[j2];
        y[d] = acc / S[d*32+d];
        maha += y[d] * y[d];
        ld += log(S[d*32+d]);
      }
      pairv[pid] = -0.5 * (maha + 2.0*ld + DLOG2PI);
    }
  }
}

// ---------------- final: merge partials + pair terms -> scalar ----------------------
__global__ __launch_bounds__(512) void final_kernel(
    const float* __restrict__ wts, const double* __restrict__ pairv,
    const double* __restrict__ partials, float* __restrict__ out)
{
  __shared__ double rm[8], rs[8], rzm[8], rzs[8];
  int tid = threadIdx.x;
  double tm = partials[2*tid], ts = partials[2*tid+1];
  double zm = -1e30, zs = 0.0;
  for (int p = tid; p < NPAIR; p += 512) {
    int i = p >> 5, j = p & 31;
    lse_merge(zm, zs, pairv[p], (double)wts[i] * (double)wts[j]);
  }
  #pragma unroll
  for (int off = 32; off > 0; off >>= 1) {
    double a = __shfl_down(tm, off), b = __shfl_down(ts, off);
    lse_merge(tm, ts, a, b);
    double c = __shfl_down(zm, off), d = __shfl_down(zs, off);
    lse_merge(zm, zs, c, d);
  }
  if ((tid & 63) == 0) { int w = tid >> 6; rm[w]=tm; rs[w]=ts; rzm[w]=zm; rzs[w]=zs; }
  __syncthreads();
  if (tid == 0) {
    for (int w = 1; w < 8; w++) { lse_merge(tm, ts, rm[w], rs[w]); lse_merge(zm, zs, rzm[w], rzs[w]); }
    double logT = tm + log(ts);
    double logz = zm + log(zs);
    out[0] = (float)((logz - logT) / (double)NPTS);
  }
}

extern "C" void kernel_launch(void* const* d_in, const int* in_sizes, int n_in,
                              void* d_out, int out_size, void* d_ws, size_t ws_size,
                              hipStream_t stream) {
  const float* X     = (const float*)d_in[0];
  const float* means = (const float*)d_in[1];
  const float* chols = (const float*)d_in[2];
  const float* wts   = (const float*)d_in[3];
  float* out = (float*)d_out;
  char* ws = (char*)d_ws;
  double* Sigma    = (double*)ws;                 // 32768 doubles = 262144 B
  float*  Bpk      = (float*)(ws + 262144);       // 16896 floats  -> 329728
  float*  cvec     = (float*)(ws + 329728);       // 1024 floats   -> 333824
  float*  logdetv  = (float*)(ws + 333824);       // 32 floats     -> 333952
  double* pairv    = (double*)(ws + 333952);      // 1024 doubles  -> 342144
  double* partials = (double*)(ws + 342144);      // 1024 doubles  -> 350336

  setup_kernel<<<KC, 64, 0, stream>>>(means, chols, Bpk, cvec, logdetv, Sigma);
  work_kernel<<<NPB + NPAIR, 256, 0, stream>>>(X, means, wts, Bpk, cvec, logdetv,
                                               Sigma, pairv, partials);
  final_kernel<<<1, 512, 0, stream>>>(wts, pairv, partials, out);
}

// Round 2
// 234.234 us; speedup vs baseline: 1.2122x; 1.2122x over previous
//
#include <hip/hip_runtime.h>
#include <math.h>

#define KC    32
#define NPTS  131072
#define NPB   512          // point blocks, 256 pts each
#define NPAIR 1024
#define BPAD  576          // padded packed-triangle floats per cluster
#define DLOG2PIF 58.8120661f
#define DLOG2PI  58.81206612467475

static __device__ __forceinline__ int rowoff(int r) {
  int g = r >> 2, rem = r & 3;
  return 8*g*(g+1) + 4*rem*(g+1);   // rows padded to multiples of 4 floats
}

static __device__ __forceinline__ void lse_merge(double& m, double& s, double m2, double s2) {
  if (m2 > m) { s = s*exp(m-m2) + s2; m = m2; }
  else        { s = s + s2*exp(m2-m); }
}

// ============ setup: Sigma(fp32)->global, register-shuffle chol, L^-1, pack ========
__global__ __launch_bounds__(64) void setup_kernel(
    const float* __restrict__ means, const float* __restrict__ chols,
    float* __restrict__ SigmaF, float* __restrict__ Bpk,
    float* __restrict__ cvec, float* __restrict__ logdetv)
{
  const int k = blockIdx.x, tid = threadIdx.x, r = tid & 31;
  __shared__ float Cs[32*33];                       // padded pitch 33: conflict-free
  for (int i = tid; i < 1024; i += 64) Cs[(i>>5)*33 + (i&31)] = chols[k*1024 + i];
  __syncthreads();
  float cr[32], a[32];
  #pragma unroll
  for (int m = 0; m < 32; m++) cr[m] = Cs[r*33 + m];
  #pragma unroll
  for (int c = 0; c < 32; c++) {                    // Sigma row r = C_r . C_c + I
    float acc = (r == c) ? 1.0f : 0.0f;
    #pragma unroll
    for (int m = 0; m < 32; m++) acc = fmaf(cr[m], Cs[c*33 + m], acc);
    a[c] = acc;
  }
  if (tid < 32) {
    float4* dst = (float4*)(SigmaF + k*1024 + r*32);
    #pragma unroll
    for (int q = 0; q < 8; q++) dst[q] = make_float4(a[4*q], a[4*q+1], a[4*q+2], a[4*q+3]);
  }
  // in-register cholesky (lane r holds row r), rank-1 updates via shuffles
  float ldsum = 0.0f;
  #pragma unroll
  for (int j = 0; j < 32; j++) {
    float dd = __shfl(a[j], j);
    float sq = sqrtf(dd);
    float inv = 1.0f / sq;
    ldsum += __logf(sq);
    float l = a[j] * inv;
    #pragma unroll
    for (int e = j+1; e < 32; e++) {
      float le = __shfl(l, e);
      a[e] = (r >= e) ? fmaf(-l, le, a[e]) : a[e];
    }
    a[j] = (r == j) ? sq : ((r > j) ? l : a[j]);
  }
  // B = L^-1, row r in bacc (forward substitution, row-sweep)
  float bacc[32];
  #pragma unroll
  for (int c = 0; c < 32; c++) bacc[c] = 0.0f;
  #pragma unroll
  for (int d = 0; d < 32; d++) {
    float dd  = __shfl(a[d], d);
    float rdd = 1.0f / dd;
    #pragma unroll
    for (int c = 0; c <= d; c++) {
      float nb = (bacc[c] + ((c == d) ? 1.0f : 0.0f)) * rdd;
      bacc[c] = (r == d) ? nb : bacc[c];
      float Bd = __shfl(bacc[c], d);                // finalized B[d][c]
      bacc[c] = (r > d) ? fmaf(-a[d], Bd, bacc[c]) : bacc[c];
    }
  }
  if (tid < 32) {
    float* dstb = Bpk + k*BPAD + rowoff(r);
    const int nq = (r + 4) >> 2;
    #pragma unroll
    for (int q = 0; q < 8; q++)
      if (q < nq) ((float4*)dstb)[q] = make_float4(bacc[4*q], bacc[4*q+1], bacc[4*q+2], bacc[4*q+3]);
    float cv = 0.0f;                                // c = B mu  (zeros kill j>r)
    #pragma unroll
    for (int j = 0; j < 32; j++) cv = fmaf(bacc[j], means[k*32 + j], cv);
    cvec[k*32 + r] = cv;
    if (r == 0) logdetv[k] = 2.0f * ldsum;
  }
}

// ============ work: point blocks (<NPB) + pair blocks (4 pairs/block, 1/wave) ======
__global__ __launch_bounds__(256) void work_kernel(
    const float* __restrict__ X, const float* __restrict__ means, const float* __restrict__ wts,
    const float* __restrict__ SigmaF, const float* __restrict__ Bpk,
    const float* __restrict__ cvec, const float* __restrict__ logdetv,
    double* __restrict__ pairv, double* __restrict__ partials)
{
  const int tid = threadIdx.x;
  if (blockIdx.x < NPB) {
    // ---- points: 256 pts/block, x in regs, B staged 16 clusters/phase in LDS ----
    __shared__ float bsh[16*BPAD];
    __shared__ float csh[1024];
    __shared__ float ldw[64];
    __shared__ double redm[4], reds[4];
    const int i = blockIdx.x*256 + tid;
    float x[32];
    const float4* xp = (const float4*)(X + (size_t)i*32);
    #pragma unroll
    for (int q = 0; q < 8; q++) { float4 f = xp[q]; x[4*q]=f.x; x[4*q+1]=f.y; x[4*q+2]=f.z; x[4*q+3]=f.w; }
    float mF = -1e30f, sF = 0.0f;
    #pragma unroll 1
    for (int ph = 0; ph < 2; ph++) {
      __syncthreads();
      const float4* bsrc = (const float4*)(Bpk + ph*(16*BPAD));
      #pragma unroll 1
      for (int t = tid; t < 16*BPAD/4; t += 256) ((float4*)bsh)[t] = bsrc[t];
      if (ph == 0) {
        for (int t = tid; t < 1024; t += 256) csh[t] = cvec[t];
        if (tid < 32) ldw[tid] = logdetv[tid];
        else if (tid < 64) ldw[tid] = wts[tid-32];
      }
      __syncthreads();
      #pragma unroll 1
      for (int kk = 0; kk < 16; kk++) {
        const int k = ph*16 + kk;
        const float* bk = bsh + kk*BPAD;
        const float* ck = csh + k*32;
        float maha = 0.0f; int off = 0;
        #pragma unroll
        for (int d = 0; d < 32; d++) {
          float y = -ck[d];                         // broadcast LDS read
          const float4* brow = (const float4*)(bk + off);
          const int nq = (d + 4) >> 2;
          #pragma unroll
          for (int q = 0; q < nq; q++) {            // broadcast ds_read_b128
            float4 b = brow[q];
            y = fmaf(b.x, x[4*q  ], y);
            y = fmaf(b.y, x[4*q+1], y);
            y = fmaf(b.z, x[4*q+2], y);
            y = fmaf(b.w, x[4*q+3], y);
          }
          off += (d + 4) & ~3;
          maha = fmaf(y, y, maha);
        }
        float g  = -0.5f * (maha + ldw[k] + DLOG2PIF);
        float wk = ldw[32+k];
        float M  = fmaxf(mF, g);
        sF = sF * __expf(mF - M) + wk * __expf(g - M);
        mF = M;
      }
    }
    double vm, vs = 1.0;
    if (sF != 0.0f) vm = 2.0 * ((double)mF + log(fabs((double)sF)));
    else            vm = -1e30;
    #pragma unroll
    for (int off2 = 32; off2 > 0; off2 >>= 1) {
      double m2 = __shfl_down(vm, off2);
      double s2 = __shfl_down(vs, off2);
      lse_merge(vm, vs, m2, s2);
    }
    if ((tid & 63) == 0) { redm[tid>>6] = vm; reds[tid>>6] = vs; }
    __syncthreads();
    if (tid == 0) {
      for (int wv = 1; wv < 4; wv++) lse_merge(vm, vs, redm[wv], reds[wv]);
      partials[2*blockIdx.x]   = vm;
      partials[2*blockIdx.x+1] = vs;
    }
  } else {
    // ---- pairs: 1 pair per wave, all-register chol + column-sweep solve ----
    const int pb = blockIdx.x - NPB;
    const int w = tid >> 6, lane = tid & 63, r = lane & 31;
    const int pid = pb*4 + w, pi = pid >> 5, pj = pid & 31;
    float a[32];
    const float4* PA = (const float4*)(SigmaF + pi*1024 + r*32);
    const float4* PB = (const float4*)(SigmaF + pj*1024 + r*32);
    #pragma unroll
    for (int q = 0; q < 8; q++) {
      float4 u = PA[q], v = PB[q];
      a[4*q]=u.x+v.x; a[4*q+1]=u.y+v.y; a[4*q+2]=u.z+v.z; a[4*q+3]=u.w+v.w;
    }
    #pragma unroll
    for (int j = 0; j < 32; j++) {
      float dd = __shfl(a[j], j);
      float sq = sqrtf(dd);
      float inv = 1.0f / sq;
      float l = a[j] * inv;
      #pragma unroll
      for (int e = j+1; e < 32; e++) {
        float le = __shfl(l, e);
        a[e] = (r >= e) ? fmaf(-l, le, a[e]) : a[e];
      }
      a[j] = (r == j) ? sq : ((r > j) ? l : a[j]);
    }
    float acc = means[pi*32 + r] - means[pj*32 + r];
    float maha = 0.0f, ldsum = 0.0f;
    #pragma unroll
    for (int d = 0; d < 32; d++) {
      float dd = __shfl(a[d], d);
      float yd = __shfl(acc, d) / dd;
      maha = fmaf(yd, yd, maha);
      ldsum += __logf(dd);
      acc = (r > d) ? fmaf(-a[d], yd, acc) : acc;
    }
    if (lane == 0) pairv[pid] = -0.5 * ((double)maha + 2.0*(double)ldsum + DLOG2PI);
  }
}

// ============ final: merge 512 point partials + 1024 pair terms -> scalar ==========
__global__ __launch_bounds__(512) void final_kernel(
    const float* __restrict__ wts, const double* __restrict__ pairv,
    const double* __restrict__ partials, float* __restrict__ out)
{
  __shared__ double rm[8], rs[8], rzm[8], rzs[8];
  const int tid = threadIdx.x;
  double tm = partials[2*tid], ts = partials[2*tid+1];
  double zm = -1e30, zs = 0.0;
  for (int p = tid; p < NPAIR; p += 512) {
    int i = p >> 5, j = p & 31;
    lse_merge(zm, zs, pairv[p], (double)wts[i] * (double)wts[j]);
  }
  #pragma unroll
  for (int off = 32; off > 0; off >>= 1) {
    double a = __shfl_down(tm, off), b = __shfl_down(ts, off);
    lse_merge(tm, ts, a, b);
    double c = __shfl_down(zm, off), d = __shfl_down(zs, off);
    lse_merge(zm, zs, c, d);
  }
  if ((tid & 63) == 0) { int w = tid >> 6; rm[w]=tm; rs[w]=ts; rzm[w]=zm; rzs[w]=zs; }
  __syncthreads();
  if (tid == 0) {
    for (int w = 1; w < 8; w++) { lse_merge(tm, ts, rm[w], rs[w]); lse_merge(zm, zs, rzm[w], rzs[w]); }
    double logT = tm + log(ts);
    double logz = zm + log(zs);
    out[0] = (float)((logz - logT) / (double)NPTS);
  }
}

extern "C" void kernel_launch(void* const* d_in, const int* in_sizes, int n_in,
                              void* d_out, int out_size, void* d_ws, size_t ws_size,
                              hipStream_t stream) {
  const float* X     = (const float*)d_in[0];
  const float* means = (const float*)d_in[1];
  const float* chols = (const float*)d_in[2];
  const float* wts   = (const float*)d_in[3];
  float* out = (float*)d_out;
  char* ws = (char*)d_ws;
  float*  SigmaF   = (float*)ws;                   // 32*1024*4   = 131072
  float*  Bpk      = (float*)(ws + 131072);        // 32*576*4    = 73728  -> 204800
  float*  cvec     = (float*)(ws + 204800);        // 1024*4      -> 208896
  float*  logdetv  = (float*)(ws + 208896);        // 32*4 (+pad) -> 209024
  double* pairv    = (double*)(ws + 209024);       // 1024*8      -> 217216
  double* partials = (double*)(ws + 217216);       // 512*2*8     -> 225408

  setup_kernel<<<KC, 64, 0, stream>>>(means, chols, SigmaF, Bpk, cvec, logdetv);
  work_kernel<<<NPB + NPAIR/4, 256, 0, stream>>>(X, means, wts, SigmaF, Bpk,
                                                 cvec, logdetv, pairv, partials);
  final_kernel<<<1, 512, 0, stream>>>(wts, pairv, partials, out);
}

// Round 3
// 156.910 us; speedup vs baseline: 1.8096x; 1.4928x over previous
//
#include <hip/hip_runtime.h>
#include <math.h>

#define NPTS  131072
#define NPB   1024         // point blocks: 256 thr = 4 waves x 32 pts = 128 pts/block
#define NPAIRB 256         // pair blocks: 4 pairs/block (1 per wave)
#define DLOG2PIF 58.8120661f
#define DLOG2PI  58.81206612467475

typedef __attribute__((ext_vector_type(8)))  short short8;   // 8 bf16 = 4 VGPRs
typedef __attribute__((ext_vector_type(16))) float f32x16;   // MFMA 32x32 acc

static __device__ __forceinline__ unsigned bfh(float f) {    // fp32 -> bf16 bits (RNE)
  unsigned u = __float_as_uint(f);
  return (u + 0x7FFFu + ((u >> 16) & 1u)) >> 16;
}
static __device__ __forceinline__ float bfhf(float f) {      // fp32 -> bf16 -> fp32
  return __uint_as_float(bfh(f) << 16);
}

static __device__ __forceinline__ void lse_merge(double& m, double& s, double m2, double s2) {
  if (m2 > m) { s = s*exp(m-m2) + s2; m = m2; }
  else        { s = s + s2*exp(m2-m); }
}

// ===== setup: Sigma, register chol, column-parallel L^-1, MFMA A-fragments =========
// Afrag layout: [cluster][slot(5)][lane(64)] x 16B.
// slot 0/1: bf16-hi of B rows, k-chunk 0/1; slot 2/3: bf16-lo; slot 4: -c (hi,lo) frag.
// Fragment content for lane l (m = l&31, h = l>>5): A[m][k = chunk*16 + h*8 + j], j=0..7.
__global__ __launch_bounds__(64) void setup_kernel(
    const float* __restrict__ means, const float* __restrict__ chols,
    float* __restrict__ SigmaF, uint4* __restrict__ Afrag, float* __restrict__ logdetv)
{
  const int k = blockIdx.x, tid = threadIdx.x, r = tid & 31, h = tid >> 5;
  __shared__ float Cs[32*33];
  __shared__ float Bsh[32*33];
  for (int i = tid; i < 1024; i += 64) Cs[(i>>5)*33 + (i&31)] = chols[k*1024 + i];
  __syncthreads();
  float a[32];
  {
    float cr[32];
    #pragma unroll
    for (int m = 0; m < 32; m++) cr[m] = Cs[r*33 + m];
    #pragma unroll
    for (int c = 0; c < 32; c++) {               // Sigma row r = C_r . C_c + I
      float acc = (r == c) ? 1.0f : 0.0f;
      #pragma unroll
      for (int m = 0; m < 32; m++) acc = fmaf(cr[m], Cs[c*33+m], acc);
      a[c] = acc;
    }
  }
  if (tid < 32) {
    #pragma unroll
    for (int q = 0; q < 8; q++)
      ((float4*)(SigmaF + k*1024 + r*32))[q] = make_float4(a[4*q],a[4*q+1],a[4*q+2],a[4*q+3]);
  }
  // in-register cholesky: lane r holds row r
  float ldsum = 0.0f;
  #pragma unroll
  for (int j = 0; j < 32; j++) {
    float dd = __shfl(a[j], j);
    float sq = sqrtf(dd);
    float inv = 1.0f / sq;
    ldsum += __logf(sq);
    float l = a[j] * inv;
    #pragma unroll
    for (int e = j+1; e < 32; e++) {
      float le = __shfl(l, e);
      a[e] = (r >= e) ? fmaf(-l, le, a[e]) : a[e];
    }
    a[j] = (r == j) ? sq : ((r > j) ? l : a[j]);
  }
  // column-parallel inversion: lane c computes column c of B = L^-1
  float bcol[32];
  #pragma unroll
  for (int d = 0; d < 32; d++) {
    float s = (d == r) ? 1.0f : 0.0f;
    #pragma unroll
    for (int j = 0; j < d; j++) {
      float Ldj = __shfl(a[j], d);
      s = fmaf(-Ldj, (j > 0 || d > 0) ? bcol[j] : 0.0f, s);  // bcol[j]==0 for j<c by construction
    }
    float Ldd = __shfl(a[d], d);
    bcol[d] = s / Ldd;
  }
  // transpose columns -> rows through LDS (pitch 33: conflict-free both ways)
  if (tid < 32) {
    #pragma unroll
    for (int d = 0; d < 32; d++) Bsh[d*33 + r] = bcol[d];
  }
  __syncthreads();
  float bacc[32];
  #pragma unroll
  for (int j = 0; j < 32; j++) bacc[j] = Bsh[r*33 + j];
  // c = B mu (upper zeros make it triangular automatically)
  float cv = 0.0f;
  #pragma unroll
  for (int j = 0; j < 32; j++) cv = fmaf(bacc[j], means[k*32 + j], cv);
  if (tid == 0) logdetv[k] = 2.0f*ldsum + DLOG2PIF;
  // gather this lane's 16 dims (h selects which half of each 16-dim chunk)
  float t0[8], t1[8];
  #pragma unroll
  for (int j = 0; j < 8; j++) {
    t0[j] = (h == 0) ? bacc[j]      : bacc[8+j];    // chunk0 dims h*8+j
    t1[j] = (h == 0) ? bacc[16+j]   : bacc[24+j];   // chunk1 dims 16+h*8+j
  }
  uint4 s0, s1, s2, s3, s4;
  unsigned b0[8], b1[8], l0[8], l1[8];
  #pragma unroll
  for (int j = 0; j < 8; j++) {
    b0[j] = bfh(t0[j]);  l0[j] = bfh(t0[j] - bfhf(t0[j]));
    b1[j] = bfh(t1[j]);  l1[j] = bfh(t1[j] - bfhf(t1[j]));
  }
  s0 = make_uint4(b0[0]|(b0[1]<<16), b0[2]|(b0[3]<<16), b0[4]|(b0[5]<<16), b0[6]|(b0[7]<<16));
  s1 = make_uint4(b1[0]|(b1[1]<<16), b1[2]|(b1[3]<<16), b1[4]|(b1[5]<<16), b1[6]|(b1[7]<<16));
  s2 = make_uint4(l0[0]|(l0[1]<<16), l0[2]|(l0[3]<<16), l0[4]|(l0[5]<<16), l0[6]|(l0[7]<<16));
  s3 = make_uint4(l1[0]|(l1[1]<<16), l1[2]|(l1[3]<<16), l1[4]|(l1[5]<<16), l1[6]|(l1[7]<<16));
  unsigned ch = bfh(cv) ^ 0x8000u;                       // -c_hi
  unsigned cl = bfh(cv - bfhf(cv)) ^ 0x8000u;            // -c_lo
  s4 = make_uint4((h == 0) ? (ch | (cl<<16)) : 0u, 0u, 0u, 0u);
  Afrag[(k*5 + 0)*64 + tid] = s0;
  Afrag[(k*5 + 1)*64 + tid] = s1;
  Afrag[(k*5 + 2)*64 + tid] = s2;
  Afrag[(k*5 + 3)*64 + tid] = s3;
  Afrag[(k*5 + 4)*64 + tid] = s4;
}

// ===== work: MFMA point blocks (<NPB) + register-chol pair blocks ==================
__global__ __launch_bounds__(256) void work_kernel(
    const float* __restrict__ X, const float* __restrict__ means, const float* __restrict__ wts,
    const float* __restrict__ SigmaF, const uint4* __restrict__ Afrag,
    const float* __restrict__ logdetv,
    double* __restrict__ pairv, double* __restrict__ partials)
{
  __shared__ uint4 fsh[4*5*64];      // 4 clusters/phase x 5 slots x 64 lanes = 20480 B
  __shared__ float ld2[32], wsh[32];
  __shared__ double redm[4], reds[4];
  const int tid = threadIdx.x;
  if (blockIdx.x < NPB) {
    const int lane = tid & 63, wv = tid >> 6;
    const int h = lane >> 5;
    const int n = (blockIdx.x*4 + wv)*32 + (lane & 31);
    // load this lane's 16 dims of x, split fp32 -> bf16 hi+lo fragments
    const float* xp = X + (size_t)n*32 + h*8;
    float4 fa = *(const float4*)(xp);
    float4 fb = *(const float4*)(xp + 4);
    float4 fc = *(const float4*)(xp + 16);
    float4 fd = *(const float4*)(xp + 20);
    float v0[8] = {fa.x,fa.y,fa.z,fa.w,fb.x,fb.y,fb.z,fb.w};
    float v1[8] = {fc.x,fc.y,fc.z,fc.w,fd.x,fd.y,fd.z,fd.w};
    short8 xhi0, xlo0, xhi1, xlo1, x2c;
    #pragma unroll
    for (int j = 0; j < 8; j++) {
      xhi0[j] = (short)bfh(v0[j]);  xlo0[j] = (short)bfh(v0[j] - bfhf(v0[j]));
      xhi1[j] = (short)bfh(v1[j]);  xlo1[j] = (short)bfh(v1[j] - bfhf(v1[j]));
      x2c[j] = 0;
    }
    if (h == 0) { x2c[0] = (short)0x3F80; x2c[1] = (short)0x3F80; }  // X2 = [1,1,0,...]
    if (tid < 32) { ld2[tid] = logdetv[tid]; wsh[tid] = wts[tid]; }
    float mF = -1e30f, sF = 0.0f;
    #pragma unroll 1
    for (int ph = 0; ph < 8; ph++) {
      __syncthreads();
      const uint4* src = Afrag + ph*1280;
      #pragma unroll
      for (int t = tid; t < 1280; t += 256) fsh[t] = src[t];
      __syncthreads();
      #pragma unroll 1
      for (int kc = 0; kc < 4; kc++) {
        const int k = ph*4 + kc;
        const short8* fp = (const short8*)(fsh + kc*5*64);
        short8 a0 = fp[0*64+lane], a1 = fp[1*64+lane], a2 = fp[2*64+lane],
               a3 = fp[3*64+lane], a4 = fp[4*64+lane];
        f32x16 acc = {};
        acc = __builtin_amdgcn_mfma_f32_32x32x16_bf16(a0, xhi0, acc, 0,0,0); // Bhi.Xhi k0
        acc = __builtin_amdgcn_mfma_f32_32x32x16_bf16(a1, xhi1, acc, 0,0,0); // Bhi.Xhi k1
        acc = __builtin_amdgcn_mfma_f32_32x32x16_bf16(a2, xhi0, acc, 0,0,0); // Blo.Xhi k0
        acc = __builtin_amdgcn_mfma_f32_32x32x16_bf16(a3, xhi1, acc, 0,0,0); // Blo.Xhi k1
        acc = __builtin_amdgcn_mfma_f32_32x32x16_bf16(a0, xlo0, acc, 0,0,0); // Bhi.Xlo k0
        acc = __builtin_amdgcn_mfma_f32_32x32x16_bf16(a1, xlo1, acc, 0,0,0); // Bhi.Xlo k1
        acc = __builtin_amdgcn_mfma_f32_32x32x16_bf16(a4, x2c,  acc, 0,0,0); // -c
        float maha = 0.0f;
        #pragma unroll
        for (int q = 0; q < 16; q++) maha = fmaf(acc[q], acc[q], maha);
        maha += __shfl_xor(maha, 32);          // combine row halves
        float g  = -0.5f*(maha + ld2[k]);
        float wk = wsh[k];
        float M  = fmaxf(mF, g);
        sF = sF*__expf(mF - M) + wk*__expf(g - M);
        mF = M;
      }
    }
    // per-point v = log(s^2); upper-half lanes are duplicates -> zero them out
    double vm, vs = 1.0;
    if (sF != 0.0f) vm = 2.0*((double)mF + log(fabs((double)sF)));
    else          { vm = -1e300; vs = 0.0; }
    if (lane >= 32) { vm = -1e300; vs = 0.0; }
    #pragma unroll
    for (int off = 32; off > 0; off >>= 1) {
      double m2 = __shfl_down(vm, off);
      double s2 = __shfl_down(vs, off);
      lse_merge(vm, vs, m2, s2);
    }
    if (lane == 0) { redm[wv] = vm; reds[wv] = vs; }
    __syncthreads();
    if (tid == 0) {
      for (int w = 1; w < 4; w++) lse_merge(vm, vs, redm[w], reds[w]);
      partials[2*blockIdx.x]   = vm;
      partials[2*blockIdx.x+1] = vs;
    }
  } else {
    // ---- pairs: 1 pair per wave, all-register chol + column-sweep solve ----
    const int pb = blockIdx.x - NPB;
    const int w = tid >> 6, lane = tid & 63, r = lane & 31;
    const int pid = pb*4 + w, pi = pid >> 5, pj = pid & 31;
    float a[32];
    const float4* PA = (const float4*)(SigmaF + pi*1024 + r*32);
    const float4* PB = (const float4*)(SigmaF + pj*1024 + r*32);
    #pragma unroll
    for (int q = 0; q < 8; q++) {
      float4 u = PA[q], v = PB[q];
      a[4*q]=u.x+v.x; a[4*q+1]=u.y+v.y; a[4*q+2]=u.z+v.z; a[4*q+3]=u.w+v.w;
    }
    #pragma unroll
    for (int j = 0; j < 32; j++) {
      float dd = __shfl(a[j], j);
      float sq = sqrtf(dd);
      float inv = 1.0f / sq;
      float l = a[j] * inv;
      #pragma unroll
      for (int e = j+1; e < 32; e++) {
        float le = __shfl(l, e);
        a[e] = (r >= e) ? fmaf(-l, le, a[e]) : a[e];
      }
      a[j] = (r == j) ? sq : ((r > j) ? l : a[j]);
    }
    float acc = means[pi*32 + r] - means[pj*32 + r];
    float maha = 0.0f, ldsum = 0.0f;
    #pragma unroll
    for (int d = 0; d < 32; d++) {
      float dd = __shfl(a[d], d);
      float yd = __shfl(acc, d) / dd;
      maha = fmaf(yd, yd, maha);
      ldsum += __logf(dd);
      acc = (r > d) ? fmaf(-a[d], yd, acc) : acc;
    }
    if (lane == 0) pairv[pid] = -0.5 * ((double)maha + 2.0*(double)ldsum + DLOG2PI);
  }
}

// ===== final: merge 1024 point partials + 1024 pair terms -> scalar ================
__global__ __launch_bounds__(512) void final_kernel(
    const float* __restrict__ wts, const double* __restrict__ pairv,
    const double* __restrict__ partials, float* __restrict__ out)
{
  __shared__ double rm[8], rs[8], rzm[8], rzs[8];
  const int tid = threadIdx.x;
  double tm = partials[2*tid], ts = partials[2*tid+1];
  lse_merge(tm, ts, partials[2*(tid+512)], partials[2*(tid+512)+1]);
  double zm = -1e300, zs = 0.0;
  for (int p = tid; p < 1024; p += 512) {
    int i = p >> 5, j = p & 31;
    lse_merge(zm, zs, pairv[p], (double)wts[i] * (double)wts[j]);
  }
  #pragma unroll
  for (int off = 32; off > 0; off >>= 1) {
    double a = __shfl_down(tm, off), b = __shfl_down(ts, off);
    lse_merge(tm, ts, a, b);
    double c = __shfl_down(zm, off), d = __shfl_down(zs, off);
    lse_merge(zm, zs, c, d);
  }
  if ((tid & 63) == 0) { int w = tid >> 6; rm[w]=tm; rs[w]=ts; rzm[w]=zm; rzs[w]=zs; }
  __syncthreads();
  if (tid == 0) {
    for (int w = 1; w < 8; w++) { lse_merge(tm, ts, rm[w], rs[w]); lse_merge(zm, zs, rzm[w], rzs[w]); }
    double logT = tm + log(ts);
    double logz = zm + log(zs);
    out[0] = (float)((logz - logT) / (double)NPTS);
  }
}

extern "C" void kernel_launch(void* const* d_in, const int* in_sizes, int n_in,
                              void* d_out, int out_size, void* d_ws, size_t ws_size,
                              hipStream_t stream) {
  const float* X     = (const float*)d_in[0];
  const float* means = (const float*)d_in[1];
  const float* chols = (const float*)d_in[2];
  const float* wts   = (const float*)d_in[3];
  float* out = (float*)d_out;
  char* ws = (char*)d_ws;
  float*  SigmaF   = (float*)ws;                 // 131072 B
  uint4*  Afrag    = (uint4*)(ws + 131072);      // 32*5*64*16 = 163840 -> 294912
  float*  logdetv  = (float*)(ws + 294912);      // 128       -> 295040
  double* pairv    = (double*)(ws + 295040);     // 8192      -> 303232
  double* partials = (double*)(ws + 303232);     // 16384     -> 319616

  setup_kernel<<<32, 64, 0, stream>>>(means, chols, SigmaF, Afrag, logdetv);
  work_kernel<<<NPB + NPAIRB, 256, 0, stream>>>(X, means, wts, SigmaF, Afrag,
                                                logdetv, pairv, partials);
  final_kernel<<<1, 512, 0, stream>>>(wts, pairv, partials, out);
}